// Round 3
// baseline (884.504 us; speedup 1.0000x reference)
//
#include <hip/hip_runtime.h>
#include <math.h>

#define NQ 12
#define DIM 4096
#define NLAYER 4

// --- GF(2) linear algebra for the deferred CNOT-cascade permutation ---
// P: (P s)[y] = s[S y],  S y = y ^ y>>1 ^ y>>2 ^ ... (prefix-XOR, verified R1)
// Gate of layer L (0-idx) on qubit q (bit p=11-q) conjugated by P^L acts on
// pairs differing by mask m = S^L e_p, role(z) = parity(z & r), r = row p of D^L,
// D = S^-1, (D z) = z ^ (z>>1). Final read-out: out[y] = u[S^4 y] <=> y = z^(z>>4).
constexpr int sfun(int z) { z ^= z >> 1; z ^= z >> 2; z ^= z >> 4; z ^= z >> 8; return z & 0xFFF; }
constexpr int mk_m(int k, int p) { int m = 1 << p; for (int i = 0; i < k; ++i) m = sfun(m); return m; }
constexpr int mk_r(int k, int p) { int r = 1 << p; for (int i = 0; i < k; ++i) r = (r ^ (r << 1)) & 0xFFF; return r; }

struct Masks { int m[NLAYER][NQ]; int r[NLAYER][NQ]; };
constexpr Masks mk_masks() {
  Masks g{};
  for (int L = 0; L < NLAYER; ++L)
    for (int q = 0; q < NQ; ++q) { int p = 11 - q; g.m[L][q] = mk_m(L, p); g.r[L][q] = mk_r(L, p); }
  return g;
}
constexpr Masks GM = mk_masks();

// One wave per batch row. Element (lane, e) holds amplitude index z=(lane<<6)|e.
__global__ __launch_bounds__(64, 2) void qsim_kernel(
    const float* __restrict__ x, const float* __restrict__ w,
    float* __restrict__ out) {
  __shared__ float2 gmat[NLAYER * NQ * 4];
  __shared__ float obuf[DIM];  // 16 KB output-permutation staging

  const int lane = threadIdx.x;
  const long row = blockIdx.x;

  // --- gate matrices: lanes 0..47, one gate each ---
  if (lane < NLAYER * NQ) {
    const float* wp = w + lane * 3;
    float phi = wp[0], th = wp[1], om = wp[2];
    float sn, c, sa, ca, sb, cb;
    sincosf(0.5f * th, &sn, &c);
    sincosf(0.5f * (phi + om), &sa, &ca);
    sincosf(0.5f * (phi - om), &sb, &cb);
    float2* g = &gmat[lane * 4];
    g[0] = make_float2(ca * c, -sa * c);    // U00
    g[1] = make_float2(-cb * sn, -sb * sn); // U01
    g[2] = make_float2(cb * sn, -sb * sn);  // U10
    g[3] = make_float2(ca * c, sa * c);     // U11
  }
  __syncthreads();  // single wave: effectively a waitcnt; guarantees gmat visible

  // --- load row (lane reads 64 consecutive floats), norm, encode ---
  const float* xr = x + row * (long)DIM + lane * 64;
  float2 s[64];
  float ss = 0.f;
#pragma unroll
  for (int e4 = 0; e4 < 16; ++e4) {
    float4 v = ((const float4*)xr)[e4];
    s[e4 * 4 + 0] = make_float2(v.x, 0.f);
    s[e4 * 4 + 1] = make_float2(v.y, 0.f);
    s[e4 * 4 + 2] = make_float2(v.z, 0.f);
    s[e4 * 4 + 3] = make_float2(v.w, 0.f);
    ss += v.x * v.x + v.y * v.y + v.z * v.z + v.w * v.w;
  }
#pragma unroll
  for (int off = 32; off; off >>= 1) ss += __shfl_xor(ss, off, 64);
  const float nrm = sqrtf(ss);
  const bool ok = nrm > 1e-10f;
  const float inv = ok ? 1.0f / nrm : 0.f;
#pragma unroll
  for (int e = 0; e < 64; ++e) s[e].x = ok ? s[e].x * inv : 0.015625f;

  // --- 48 gates, all masks compile-time; no permutation passes ---
#pragma unroll
  for (int L = 0; L < NLAYER; ++L) {
#pragma unroll
    for (int q = 0; q < NQ; ++q) {
      const int m = GM.m[L][q];
      const int r = GM.r[L][q];
      const int mhi = m >> 6, mlo = m & 63;
      const int rhi = r >> 6, rlo = r & 63;
      const float2* g = &gmat[(L * NQ + q) * 4];
      const float2 u00 = g[0], u01 = g[1], u10 = g[2], u11 = g[3];
      const int lr = __popc(lane & rhi) & 1;  // runtime lane part of role
      // coeff set A: element-role-parity 0; B: parity 1 (full role = lr ^ er)
      float2 Acs, Acp, Bcs, Bcp;
      Acs.x = lr ? u11.x : u00.x; Acs.y = lr ? u11.y : u00.y;
      Acp.x = lr ? u10.x : u01.x; Acp.y = lr ? u10.y : u01.y;
      Bcs.x = lr ? u00.x : u11.x; Bcs.y = lr ? u00.y : u11.y;
      Bcp.x = lr ? u01.x : u10.x; Bcp.y = lr ? u01.y : u10.y;

      if (mhi == 0) {
        // pure register gate: pairs {e, e^mlo} within the lane
        const int piv = mlo & (-mlo);
#pragma unroll
        for (int e = 0; e < 64; ++e) {
          if (e & piv) continue;
          const int e2 = e ^ mlo;
          const int er = __builtin_popcount(e & rlo) & 1;   // compile-time
          const int er2 = __builtin_popcount(e2 & rlo) & 1; // compile-time
          const float2 cs = er ? Bcs : Acs, cp = er ? Bcp : Acp;
          const float2 es = er2 ? Bcs : Acs, ep = er2 ? Bcp : Acp;
          const float2 a = s[e], b = s[e2];
          s[e].x  = cs.x * a.x - cs.y * a.y + cp.x * b.x - cp.y * b.y;
          s[e].y  = cs.x * a.y + cs.y * a.x + cp.x * b.y + cp.y * b.x;
          s[e2].x = es.x * b.x - es.y * b.y + ep.x * a.x - ep.y * a.y;
          s[e2].y = es.x * b.y + es.y * b.x + ep.x * a.y + ep.y * a.x;
        }
      } else if (mlo == 0) {
        // pure lane-shfl gate
#pragma unroll
        for (int e = 0; e < 64; ++e) {
          const int er = __builtin_popcount(e & rlo) & 1;  // compile-time
          const float2 cs = er ? Bcs : Acs, cp = er ? Bcp : Acp;
          const float px = __shfl_xor(s[e].x, mhi, 64);
          const float py = __shfl_xor(s[e].y, mhi, 64);
          const float nx = cs.x * s[e].x - cs.y * s[e].y + cp.x * px - cp.y * py;
          const float ny = cs.x * s[e].y + cs.y * s[e].x + cp.x * py + cp.y * px;
          s[e].x = nx; s[e].y = ny;
        }
      } else {
        // mixed gate: partner flips both lane bits (shfl) and e bits
        const int piv = mlo & (-mlo);
#pragma unroll
        for (int e = 0; e < 64; ++e) {
          if (e & piv) continue;
          const int e2 = e ^ mlo;
          const int er = __builtin_popcount(e & rlo) & 1;
          const int er2 = __builtin_popcount(e2 & rlo) & 1;
          const float2 cs = er ? Bcs : Acs, cp = er ? Bcp : Acp;
          const float2 es = er2 ? Bcs : Acs, ep = er2 ? Bcp : Acp;
          const float pax = __shfl_xor(s[e2].x, mhi, 64);  // partner of e
          const float pay = __shfl_xor(s[e2].y, mhi, 64);
          const float pbx = __shfl_xor(s[e].x, mhi, 64);   // partner of e2
          const float pby = __shfl_xor(s[e].y, mhi, 64);
          const float2 a = s[e], b = s[e2];
          s[e].x  = cs.x * a.x - cs.y * a.y + cp.x * pax - cp.y * pay;
          s[e].y  = cs.x * a.y + cs.y * a.x + cp.x * pay + cp.y * pax;
          s[e2].x = es.x * b.x - es.y * b.y + ep.x * pbx - ep.y * pby;
          s[e2].y = es.x * b.y + es.y * b.x + ep.x * pby + ep.y * pbx;
        }
      }
    }
  }

  // --- probs, row total, final permutation P^4 via one swizzled LDS pass ---
  float tot = 0.f;
#pragma unroll
  for (int e = 0; e < 64; ++e) {
    const float pv = s[e].x * s[e].x + s[e].y * s[e].y;
    tot += pv;
    const int z = (lane << 6) | e;
    const int y = z ^ (z >> 4);            // out position (D^4 z), 12-bit
    obuf[y ^ ((y >> 5) & 31)] = pv;        // swizzle: 2 lanes/bank (verified rank-5)
  }
#pragma unroll
  for (int off = 32; off; off >>= 1) tot += __shfl_xor(tot, off, 64);
  const bool okp = tot > 1e-10f;
  const float invt = okp ? 1.0f / tot : 0.f;
  float* orow = out + row * (long)DIM;
  __syncthreads();  // single wave: waitcnt for obuf RAW
#pragma unroll
  for (int k = 0; k < 64; ++k) {
    const int yl = k * 64 + lane;          // coalesced across lanes
    const float v = obuf[yl ^ ((yl >> 5) & 31)];
    orow[yl] = okp ? v * invt : (1.0f / DIM);
  }
}

extern "C" void kernel_launch(void* const* d_in, const int* in_sizes, int n_in,
                              void* d_out, int out_size, void* d_ws, size_t ws_size,
                              hipStream_t stream) {
  const float* x = (const float*)d_in[0];
  const float* w = (const float*)d_in[1];
  float* out = (float*)d_out;
  const int B = in_sizes[0] / DIM;
  qsim_kernel<<<B, 64, 0, stream>>>(x, w, out);
}

// Round 4
// 136.601 us; speedup vs baseline: 6.4751x; 6.4751x over previous
//
#include <hip/hip_runtime.h>
#include <math.h>

#define NQ 12
#define DIM 4096
#define NLAYER 4
#define NT 512

// Storage swizzle: XOR index bits 6-8 into bits 3-5. Involution.
// Keeps per-thread contiguous 64B reads conflict-free and spreads all
// scatter-write patterns across >=16 bank-pair slots (hand-verified).
__device__ __forceinline__ float block_reduce_sum(float v, float* red) {
  const int tid = threadIdx.x;
#pragma unroll
  for (int off = 32; off > 0; off >>= 1) v += __shfl_down(v, off, 64);
  if ((tid & 63) == 0) red[tid >> 6] = v;
  __syncthreads();
  if (tid == 0) {
    float s = 0.f;
#pragma unroll
    for (int i = 0; i < NT / 64; ++i) s += red[i];
    red[0] = s;
  }
  __syncthreads();
  float r = red[0];
  __syncthreads();
  return r;
}

__device__ __forceinline__ void apply_pair(float2& a0, float2& a1,
    const float2 u00, const float2 u01, const float2 u10, const float2 u11) {
  float2 n0, n1;
  n0.x = u00.x * a0.x - u00.y * a0.y + u01.x * a1.x - u01.y * a1.y;
  n0.y = u00.x * a0.y + u00.y * a0.x + u01.x * a1.y + u01.y * a1.x;
  n1.x = u10.x * a0.x - u10.y * a0.y + u11.x * a1.x - u11.y * a1.y;
  n1.y = u10.x * a0.y + u10.y * a0.x + u11.x * a1.y + u11.y * a1.x;
  a0 = n0; a1 = n1;
}

// 3 gates on e-bits 0,1,2 == z-bits pbase..pbase+2 == qubits 11-pbase..9-pbase
__device__ __forceinline__ void gates3(float2 s[8], const float2* GL, int pbase) {
#pragma unroll
  for (int j = 0; j < 3; ++j) {
    const float2* g = &GL[(11 - pbase - j) * 4];
    const float2 u00 = g[0], u01 = g[1], u10 = g[2], u11 = g[3];
#pragma unroll
    for (int pe = 0; pe < 4; ++pe) {
      const int e0 = ((pe >> j) << (j + 1)) | (pe & ((1 << j) - 1));
      apply_pair(s[e0], s[e0 | (1 << j)], u00, u01, u10, u11);
    }
  }
}

__global__ __launch_bounds__(NT, 4) void qsim_kernel(
    const float* __restrict__ x, const float* __restrict__ w,
    float* __restrict__ out) {
  __shared__ __align__(16) float2 st[DIM];              // 32 KB
  __shared__ __align__(16) float2 gmat[NLAYER * NQ * 4];
  __shared__ float red[NT / 64];

  const int t = threadIdx.x;
  const int a = t & 7, b = (t >> 3) & 7, c = t >> 6;
  const long row = blockIdx.x;

  // --- gate matrices (48 gates, one thread each) ---
  if (t < NLAYER * NQ) {
    const float* wp = w + t * 3;
    float phi = wp[0], th = wp[1], om = wp[2];
    float sn, cc, sa, ca, sb, cb;
    sincosf(0.5f * th, &sn, &cc);
    sincosf(0.5f * (phi + om), &sa, &ca);
    sincosf(0.5f * (phi - om), &sb, &cb);
    float2* g = &gmat[t * 4];
    g[0] = make_float2(ca * cc, -sa * cc);   // U00
    g[1] = make_float2(-cb * sn, -sb * sn);  // U01
    g[2] = make_float2(cb * sn, -sb * sn);   // U10
    g[3] = make_float2(ca * cc, sa * cc);    // U11
  }

  // --- load 8 consecutive x, norm, encode ---
  const float4* xr = (const float4*)(x + row * (long)DIM) + t * 2;
  const float4 v0 = xr[0], v1 = xr[1];
  float xv[8] = {v0.x, v0.y, v0.z, v0.w, v1.x, v1.y, v1.z, v1.w};
  float ss = 0.f;
#pragma unroll
  for (int e = 0; e < 8; ++e) ss += xv[e] * xv[e];
  const float nrm = sqrtf(block_reduce_sum(ss, red));  // barriers cover gmat too
  const bool ok = nrm > 1e-10f;
  const float inv = ok ? 1.0f / nrm : 0.f;

  // storage position of logical u=8t+e is sigma(u) = rbase + e (contiguous)
  const int rbase = 8 * (t ^ b);
#pragma unroll
  for (int e = 0; e < 8; ++e)
    st[rbase + e] = make_float2(ok ? xv[e] * inv : 0.015625f, 0.f);
  __syncthreads();

  // precomputed swizzled scatter-write bases (index units)
  const int wAC = a | (b << 3) | (b << 6) | (c << 9);  // passes 0,2: pos = wAC ^ (e<<3)
  const int wB = b | ((c ^ a) << 3) | (a << 6);        // pass 1:    pos = wB + (e<<9)
  const int zb = b | (c << 3) | (a << 6);              // pass 3 (perm fused)
  const int yb = zb ^ (zb >> 1);
  const int wD = yb ^ (((yb >> 6) & 7) << 3);          // pos = wD ^ KD[e]
  constexpr int KD[8] = {0x000, 0x320, 0x600, 0x520, 0xC00, 0xF20, 0xA00, 0x920};

  float2 s[8];
  for (int L = 0; L < NLAYER; ++L) {
    const float2* GL = &gmat[L * NQ * 4];

    // pass 0: z-bits 0-2 (qubits 11,10,9)
#pragma unroll
    for (int e = 0; e < 8; ++e) s[e] = st[rbase + e];
    gates3(s, GL, 0);
    __syncthreads();
#pragma unroll
    for (int e = 0; e < 8; ++e) st[wAC ^ (e << 3)] = s[e];
    __syncthreads();

    // pass 1: z-bits 3-5 (qubits 8,7,6)
#pragma unroll
    for (int e = 0; e < 8; ++e) s[e] = st[rbase + e];
    gates3(s, GL, 3);
    __syncthreads();
#pragma unroll
    for (int e = 0; e < 8; ++e) st[wB + (e << 9)] = s[e];
    __syncthreads();

    // pass 2: z-bits 6-8 (qubits 5,4,3)
#pragma unroll
    for (int e = 0; e < 8; ++e) s[e] = st[rbase + e];
    gates3(s, GL, 6);
    __syncthreads();
#pragma unroll
    for (int e = 0; e < 8; ++e) st[wAC ^ (e << 3)] = s[e];
    __syncthreads();

    // pass 3: z-bits 9-11 (qubits 2,1,0) + fused CNOT-cascade permutation
#pragma unroll
    for (int e = 0; e < 8; ++e) s[e] = st[rbase + e];
    gates3(s, GL, 9);
    __syncthreads();
#pragma unroll
    for (int e = 0; e < 8; ++e) st[wD ^ KD[e]] = s[e];
    __syncthreads();
  }

  // --- probabilities + renormalize + coalesced store ---
  float pr[8];
  float ps = 0.f;
#pragma unroll
  for (int e = 0; e < 8; ++e) {
    const float2 v = st[rbase + e];
    pr[e] = v.x * v.x + v.y * v.y;
    ps += pr[e];
  }
  const float tot = block_reduce_sum(ps, red);
  const bool okp = tot > 1e-10f;
  const float invt = okp ? 1.0f / tot : 0.f;
  float o[8];
#pragma unroll
  for (int e = 0; e < 8; ++e) o[e] = okp ? pr[e] * invt : (1.0f / DIM);
  float4* orow = (float4*)(out + row * (long)DIM) + t * 2;
  orow[0] = make_float4(o[0], o[1], o[2], o[3]);
  orow[1] = make_float4(o[4], o[5], o[6], o[7]);
}

extern "C" void kernel_launch(void* const* d_in, const int* in_sizes, int n_in,
                              void* d_out, int out_size, void* d_ws, size_t ws_size,
                              hipStream_t stream) {
  const float* x = (const float*)d_in[0];
  const float* w = (const float*)d_in[1];
  float* out = (float*)d_out;
  const int B = in_sizes[0] / DIM;
  qsim_kernel<<<B, NT, 0, stream>>>(x, w, out);
}

// Round 5
// 97.902 us; speedup vs baseline: 9.0346x; 1.3953x over previous
//
#include <hip/hip_runtime.h>
#include <math.h>

#define NQ 12
#define DIM 4096
#define NLAYER 4
#define NT 512

// CNOT-cascade gather map (verified R1/R4): element for post-perm label y sits
// at pre-perm position sfun(y) = prefix-XOR.
__device__ __forceinline__ int sfun(int z) {
  z ^= z >> 1; z ^= z >> 2; z ^= z >> 4; z ^= z >> 8; return z & (DIM - 1);
}
// Global storage swizzle: XOR upper 6 index bits into lower 6. Involution.
// Every read/write pattern below has phys-low6 bijective in lane at fixed j
// (verified per-pattern in the round notes) -> zero bank conflicts.
__device__ __forceinline__ int swz(int s) { return s ^ ((s >> 6) & 63); }

__device__ __forceinline__ float block_reduce_sum(float v, float* red) {
  const int tid = threadIdx.x;
#pragma unroll
  for (int off = 32; off > 0; off >>= 1) v += __shfl_down(v, off, 64);
  if ((tid & 63) == 0) red[tid >> 6] = v;
  __syncthreads();
  if (tid == 0) {
    float s = 0.f;
#pragma unroll
    for (int i = 0; i < NT / 64; ++i) s += red[i];
    red[0] = s;
  }
  __syncthreads();
  float r = red[0];
  __syncthreads();
  return r;
}

__device__ __forceinline__ void apply_pair(float2& a0, float2& a1,
    const float2 u00, const float2 u01, const float2 u10, const float2 u11) {
  float2 n0, n1;
  n0.x = u00.x * a0.x - u00.y * a0.y + u01.x * a1.x - u01.y * a1.y;
  n0.y = u00.x * a0.y + u00.y * a0.x + u01.x * a1.y + u01.y * a1.x;
  n1.x = u10.x * a0.x - u10.y * a0.y + u11.x * a1.x - u11.y * a1.y;
  n1.y = u10.x * a0.y + u10.y * a0.x + u11.x * a1.y + u11.y * a1.x;
  a0 = n0; a1 = n1;
}

// Pass RT: register slot-bit i holds logical bit (9-3*RT)+i -> qubit (2+3*RT)-i.
template <int RT>
__device__ __forceinline__ void gates3(float2 s[8], const float2* GL) {
#pragma unroll
  for (int i = 0; i < 3; ++i) {
    const int q = 2 + 3 * RT - i;
    const float2 u00 = GL[q * 4 + 0], u01 = GL[q * 4 + 1];
    const float2 u10 = GL[q * 4 + 2], u11 = GL[q * 4 + 3];
#pragma unroll
    for (int pe = 0; pe < 4; ++pe) {
      const int e0 = ((pe >> i) << (i + 1)) | (pe & ((1 << i) - 1));
      apply_pair(s[e0], s[e0 | (1 << i)], u00, u01, u10, u11);
    }
  }
}

__global__ __launch_bounds__(NT, 4) void qsim_kernel(
    const float* __restrict__ x, const float* __restrict__ w,
    float* __restrict__ out) {
  extern __shared__ __align__(16) char smem[];
  float2* buf0 = (float2*)smem;           // 32 KB, layouts A/E
  float2* buf1 = buf0 + DIM;              // 32 KB, layouts B/F
  float2* gmat = buf1 + DIM;              // 1.5 KB
  float*  red  = (float*)(gmat + NLAYER * NQ * 4);

  const int t = threadIdx.x;
  const int lane = t & 63, wave = t >> 6;
  const int a = t & 7, b = (t >> 3) & 7;
  const long row = blockIdx.x;

  // --- gate matrices (48 gates, one thread each) ---
  if (t < NLAYER * NQ) {
    const float* wp = w + t * 3;
    float phi = wp[0], th = wp[1], om = wp[2];
    float sn, cc, sa, ca, sb, cb;
    sincosf(0.5f * th, &sn, &cc);
    sincosf(0.5f * (phi + om), &sa, &ca);
    sincosf(0.5f * (phi - om), &sb, &cb);
    float2* g = &gmat[t * 4];
    g[0] = make_float2(ca * cc, -sa * cc);   // U00
    g[1] = make_float2(-cb * sn, -sb * sn);  // U01
    g[2] = make_float2(cb * sn, -sb * sn);   // U10
    g[3] = make_float2(ca * cc, sa * cc);    // U11
  }

  // --- load 8 consecutive x, norm, encode into buf0 (layout A) ---
  const float4* xr = (const float4*)(x + row * (long)DIM) + t * 2;
  const float4 v0 = xr[0], v1 = xr[1];
  float xv[8] = {v0.x, v0.y, v0.z, v0.w, v1.x, v1.y, v1.z, v1.w};
  float ss = 0.f;
#pragma unroll
  for (int e = 0; e < 8; ++e) ss += xv[e] * xv[e];
  const float nrm = sqrtf(block_reduce_sum(ss, red));  // barriers cover gmat
  const bool ok = nrm > 1e-10f;
  const float inv = ok ? 1.0f / nrm : 0.f;
#pragma unroll
  for (int e = 0; e < 8; ++e)
    buf0[swz(t * 8 + e)] = make_float2(ok ? xv[e] * inv : 0.015625f, 0.f);

  // read addresses (shared by every pass): plain and perm-gather
  int radr[8], gadr[8];
#pragma unroll
  for (int j = 0; j < 8; ++j) {
    radr[j] = swz(t | (j << 9));
    gadr[j] = swz(sfun(t | (j << 9)));
  }
  __syncthreads();

  float2 s[8];
#pragma unroll
  for (int L = 0; L < NLAYER; ++L) {
    const float2* GL = &gmat[L * NQ * 4];

    // RT0 (layout A in buf0): j = logical 9-11, qubits 2,1,0.
    // Layers >=1 fuse the previous layer's CNOT permutation into this read.
    if (L == 0) {
#pragma unroll
      for (int j = 0; j < 8; ++j) s[j] = buf0[radr[j]];
    } else {
#pragma unroll
      for (int j = 0; j < 8; ++j) s[j] = buf0[gadr[j]];
    }
    gates3<0>(s, GL);
#pragma unroll
    for (int j = 0; j < 8; ++j)               // A->B: pos = lane|j<<6|wave<<9
      buf1[swz(lane | (j << 6) | (wave << 9))] = s[j];
    __syncthreads();

    // RT1 (layout B in buf1): j = logical 6-8, qubits 5,4,3
#pragma unroll
    for (int j = 0; j < 8; ++j) s[j] = buf1[radr[j]];
    gates3<1>(s, GL);
#pragma unroll
    for (int j = 0; j < 8; ++j)               // B->E
      buf0[swz(a | (j << 3) | (wave << 6) | (b << 9))] = s[j];
    __syncthreads();

    // RT2 (layout E in buf0): j = logical 3-5, qubits 8,7,6
#pragma unroll
    for (int j = 0; j < 8; ++j) s[j] = buf0[radr[j]];
    gates3<2>(s, GL);
#pragma unroll
    for (int j = 0; j < 8; ++j)               // E->F
      buf1[swz(b | (j << 3) | (wave << 6) | (a << 9))] = s[j];
    __syncthreads();

    // RT3 (layout F in buf1): j = logical 0-2, qubits 11,10,9
#pragma unroll
    for (int j = 0; j < 8; ++j) s[j] = buf1[radr[j]];
    gates3<3>(s, GL);
#pragma unroll
    for (int j = 0; j < 8; ++j)               // F->A (plain; perm deferred)
      buf0[swz((j) | (b << 3) | (a << 6) | (wave << 9))] = s[j];
    __syncthreads();
  }

  // --- output: layer-3 perm fused into gather; probs + renormalize ---
  float pv[8];
  float ps = 0.f;
#pragma unroll
  for (int k = 0; k < 8; ++k) {
    const float2 v = buf0[gadr[k]];
    pv[k] = v.x * v.x + v.y * v.y;
    ps += pv[k];
  }
  const float tot = block_reduce_sum(ps, red);
  const bool okp = tot > 1e-10f;
  const float invt = okp ? 1.0f / tot : 0.f;
  float* orow = out + row * (long)DIM;
#pragma unroll
  for (int k = 0; k < 8; ++k)
    orow[t + k * NT] = okp ? pv[k] * invt : (1.0f / DIM);
}

extern "C" void kernel_launch(void* const* d_in, const int* in_sizes, int n_in,
                              void* d_out, int out_size, void* d_ws, size_t ws_size,
                              hipStream_t stream) {
  const float* x = (const float*)d_in[0];
  const float* w = (const float*)d_in[1];
  float* out = (float*)d_out;
  const int B = in_sizes[0] / DIM;
  const size_t smem = 2 * DIM * sizeof(float2) + NLAYER * NQ * 4 * sizeof(float2)
                    + (NT / 64) * sizeof(float);
  qsim_kernel<<<B, NT, smem, stream>>>(x, w, out);
}

// Round 6
// 89.858 us; speedup vs baseline: 9.8434x; 1.0895x over previous
//
#include <hip/hip_runtime.h>
#include <math.h>

#define NQ 12
#define DIM 4096
#define NLAYER 4
#define NT 512

typedef float v2 __attribute__((ext_vector_type(2)));

__device__ __forceinline__ v2 mkv2(float a, float b) { v2 r; r.x = a; r.y = b; return r; }
__device__ __forceinline__ v2 sp(float a) { v2 r; r.x = a; r.y = a; return r; }
__device__ __forceinline__ v2 pkfma(v2 a, float b, v2 c) {
  return __builtin_elementwise_fma(a, sp(b), c);
}

// CNOT-cascade gather map (verified R1-R5): post-perm label y sits at sfun(y).
__device__ __forceinline__ int sfun(int z) {
  z ^= z >> 1; z ^= z >> 2; z ^= z >> 4; z ^= z >> 8; return z & (DIM - 1);
}
// Swizzle sigma2: XOR upper6 into low6, then XOR bits3-5 into bits0-2.
// All 7 LDS patterns: low6 bijective per phase AND bank-group(low3) full.
__device__ __forceinline__ int swz(int s) {
  int m = s ^ ((s >> 6) & 63);
  return m ^ ((m >> 3) & 7);
}

__device__ __forceinline__ v2 block_reduce_sum2(v2 v, v2* red) {
  const int tid = threadIdx.x;
#pragma unroll
  for (int off = 32; off > 0; off >>= 1) {
    v.x += __shfl_down(v.x, off, 64);
    v.y += __shfl_down(v.y, off, 64);
  }
  if ((tid & 63) == 0) red[tid >> 6] = v;
  __syncthreads();
  if (tid == 0) {
    v2 s = sp(0.f);
#pragma unroll
    for (int i = 0; i < NT / 64; ++i) s += red[i];
    red[0] = s;
  }
  __syncthreads();
  v2 r = red[0];
  __syncthreads();
  return r;
}

// Packed complex pair update for two rows at once (pure v_pk_fma material).
__device__ __forceinline__ void apply_pair(v2& r0, v2& i0, v2& r1, v2& i1,
    const float2 u00, const float2 u01, const float2 u10, const float2 u11) {
  v2 nr0 = pkfma(i1, -u01.y, pkfma(r1, u01.x, pkfma(i0, -u00.y, r0 * sp(u00.x))));
  v2 ni0 = pkfma(r1,  u01.y, pkfma(i1, u01.x, pkfma(r0,  u00.y, i0 * sp(u00.x))));
  v2 nr1 = pkfma(i1, -u11.y, pkfma(r1, u11.x, pkfma(i0, -u10.y, r0 * sp(u10.x))));
  v2 ni1 = pkfma(r1,  u11.y, pkfma(i1, u11.x, pkfma(r0,  u10.y, i0 * sp(u10.x))));
  r0 = nr0; i0 = ni0; r1 = nr1; i1 = ni1;
}

// Pass RT: slot-bit i holds logical bit (9-3*RT)+i -> qubit (2+3*RT)-i.
template <int RT>
__device__ __forceinline__ void gates3(v2 re[8], v2 im[8], const float2* GL) {
#pragma unroll
  for (int i = 0; i < 3; ++i) {
    const int q = 2 + 3 * RT - i;
    const float2 u00 = GL[q * 4 + 0], u01 = GL[q * 4 + 1];
    const float2 u10 = GL[q * 4 + 2], u11 = GL[q * 4 + 3];
#pragma unroll
    for (int pe = 0; pe < 4; ++pe) {
      const int e0 = ((pe >> i) << (i + 1)) | (pe & ((1 << i) - 1));
      const int e1 = e0 | (1 << i);
      apply_pair(re[e0], im[e0], re[e1], im[e1], u00, u01, u10, u11);
    }
  }
}

__global__ __launch_bounds__(NT, 4) void qsim_kernel(
    const float* __restrict__ x, const float* __restrict__ w,
    float* __restrict__ out) {
  extern __shared__ __align__(16) char smem[];
  float4* st   = (float4*)smem;                  // 64 KB: unit=(re0,re1,im0,im1)
  float2* gmat = (float2*)(st + DIM);            // 1.5 KB
  v2*     red  = (v2*)(gmat + NLAYER * NQ * 4);  // 64 B

  const int t = threadIdx.x;
  const int lane = t & 63, wave = t >> 6;
  const int a = t & 7, b = (t >> 3) & 7;
  const long r0 = 2L * blockIdx.x;

  // --- gate matrices (48 gates, one thread each) ---
  if (t < NLAYER * NQ) {
    const float* wp = w + t * 3;
    float phi = wp[0], th = wp[1], om = wp[2];
    float sn, cc, sa, ca, sb, cb;
    sincosf(0.5f * th, &sn, &cc);
    sincosf(0.5f * (phi + om), &sa, &ca);
    sincosf(0.5f * (phi - om), &sb, &cb);
    float2* g = &gmat[t * 4];
    g[0] = make_float2(ca * cc, -sa * cc);   // U00
    g[1] = make_float2(-cb * sn, -sb * sn);  // U01
    g[2] = make_float2(cb * sn, -sb * sn);   // U10
    g[3] = make_float2(ca * cc, sa * cc);    // U11
  }

  // --- load 8 consecutive x from each of 2 rows, norms, encode ---
  const float4* xa = (const float4*)(x + r0 * DIM) + t * 2;
  const float4* xb = (const float4*)(x + (r0 + 1) * DIM) + t * 2;
  const float4 a0 = xa[0], a1 = xa[1], b0 = xb[0], b1 = xb[1];
  const float va[8] = {a0.x, a0.y, a0.z, a0.w, a1.x, a1.y, a1.z, a1.w};
  const float vb[8] = {b0.x, b0.y, b0.z, b0.w, b1.x, b1.y, b1.z, b1.w};
  v2 ss = sp(0.f);
#pragma unroll
  for (int e = 0; e < 8; ++e) { ss.x += va[e] * va[e]; ss.y += vb[e] * vb[e]; }
  const v2 nsq = block_reduce_sum2(ss, red);   // barriers also cover gmat init
  const float n0 = sqrtf(nsq.x), n1 = sqrtf(nsq.y);
  const bool ok0 = n0 > 1e-10f, ok1 = n1 > 1e-10f;
  const float i0f = ok0 ? 1.0f / n0 : 0.f, i1f = ok1 ? 1.0f / n1 : 0.f;
#pragma unroll
  for (int e = 0; e < 8; ++e)
    st[swz(t * 8 + e)] = make_float4(ok0 ? va[e] * i0f : 0.015625f,
                                     ok1 ? vb[e] * i1f : 0.015625f, 0.f, 0.f);

  // read addresses (same every pass): plain and perm-fused gather
  int radr[8], gadr[8];
#pragma unroll
  for (int j = 0; j < 8; ++j) {
    radr[j] = swz(t | (j << 9));
    gadr[j] = swz(sfun(t | (j << 9)));
  }
  __syncthreads();

  v2 re[8], im[8];
#pragma unroll
  for (int L = 0; L < NLAYER; ++L) {
    const float2* GL = &gmat[L * NQ * 4];

    // RT0 (layout A): j = logical 9-11, qubits 2,1,0.
    // L>=1 fuses the previous layer's CNOT permutation into this read.
#pragma unroll
    for (int j = 0; j < 8; ++j) {
      const float4 v = st[L == 0 ? radr[j] : gadr[j]];
      re[j] = mkv2(v.x, v.y); im[j] = mkv2(v.z, v.w);
    }
    gates3<0>(re, im, GL);
    __syncthreads();
#pragma unroll
    for (int j = 0; j < 8; ++j)  // A->B
      st[swz(lane | (j << 6) | (wave << 9))] =
          make_float4(re[j].x, re[j].y, im[j].x, im[j].y);
    __syncthreads();

    // RT1 (layout B): j = logical 6-8, qubits 5,4,3
#pragma unroll
    for (int j = 0; j < 8; ++j) {
      const float4 v = st[radr[j]];
      re[j] = mkv2(v.x, v.y); im[j] = mkv2(v.z, v.w);
    }
    gates3<1>(re, im, GL);
    __syncthreads();
#pragma unroll
    for (int j = 0; j < 8; ++j)  // B->E
      st[swz(a | (j << 3) | (wave << 6) | (b << 9))] =
          make_float4(re[j].x, re[j].y, im[j].x, im[j].y);
    __syncthreads();

    // RT2 (layout E): j = logical 3-5, qubits 8,7,6
#pragma unroll
    for (int j = 0; j < 8; ++j) {
      const float4 v = st[radr[j]];
      re[j] = mkv2(v.x, v.y); im[j] = mkv2(v.z, v.w);
    }
    gates3<2>(re, im, GL);
    __syncthreads();
#pragma unroll
    for (int j = 0; j < 8; ++j)  // E->F
      st[swz(b | (j << 3) | (wave << 6) | (a << 9))] =
          make_float4(re[j].x, re[j].y, im[j].x, im[j].y);
    __syncthreads();

    // RT3 (layout F): j = logical 0-2, qubits 11,10,9
#pragma unroll
    for (int j = 0; j < 8; ++j) {
      const float4 v = st[radr[j]];
      re[j] = mkv2(v.x, v.y); im[j] = mkv2(v.z, v.w);
    }
    gates3<3>(re, im, GL);
    __syncthreads();
#pragma unroll
    for (int j = 0; j < 8; ++j)  // F->A (perm deferred to next read)
      st[swz(j | (b << 3) | (a << 6) | (wave << 9))] =
          make_float4(re[j].x, re[j].y, im[j].x, im[j].y);
    __syncthreads();
  }

  // --- output: final perm fused into gather; probs + renormalize, 2 rows ---
  float p0[8], p1[8];
  v2 ps = sp(0.f);
#pragma unroll
  for (int k = 0; k < 8; ++k) {
    const float4 v = st[gadr[k]];
    p0[k] = v.x * v.x + v.z * v.z;
    p1[k] = v.y * v.y + v.w * v.w;
    ps.x += p0[k]; ps.y += p1[k];
  }
  const v2 tot = block_reduce_sum2(ps, red);
  const bool k0 = tot.x > 1e-10f, k1 = tot.y > 1e-10f;
  const float t0 = k0 ? 1.0f / tot.x : 0.f, t1 = k1 ? 1.0f / tot.y : 0.f;
  float* o0 = out + r0 * DIM;
  float* o1 = out + (r0 + 1) * DIM;
#pragma unroll
  for (int k = 0; k < 8; ++k) {
    o0[t + k * NT] = k0 ? p0[k] * t0 : (1.0f / DIM);
    o1[t + k * NT] = k1 ? p1[k] * t1 : (1.0f / DIM);
  }
}

extern "C" void kernel_launch(void* const* d_in, const int* in_sizes, int n_in,
                              void* d_out, int out_size, void* d_ws, size_t ws_size,
                              hipStream_t stream) {
  const float* x = (const float*)d_in[0];
  const float* w = (const float*)d_in[1];
  float* out = (float*)d_out;
  const int B = in_sizes[0] / DIM;
  const size_t smem = DIM * sizeof(float4) + NLAYER * NQ * 4 * sizeof(float2)
                    + (NT / 64) * sizeof(v2);
  qsim_kernel<<<B / 2, NT, smem, stream>>>(x, w, out);
}

// Round 7
// 87.551 us; speedup vs baseline: 10.1027x; 1.0264x over previous
//
#include <hip/hip_runtime.h>
#include <math.h>

#define NQ 12
#define DIM 4096
#define NLAYER 4
#define NT 512

typedef float v2 __attribute__((ext_vector_type(2)));

__device__ __forceinline__ v2 mkv2(float a, float b) { v2 r; r.x = a; r.y = b; return r; }
__device__ __forceinline__ v2 sp(float a) { v2 r; r.x = a; r.y = a; return r; }
__device__ __forceinline__ v2 pkfma(v2 a, float b, v2 c) {
  return __builtin_elementwise_fma(a, sp(b), c);
}

// CNOT-cascade gather map (verified R1-R6): post-perm label y sits at sfun(y).
__device__ __forceinline__ int sfun(int z) {
  z ^= z >> 1; z ^= z >> 2; z ^= z >> 4; z ^= z >> 8; return z & (DIM - 1);
}
// Swizzle sigma2 (HW-validated R6): XOR upper6 into low6, then bits3-5 into 0-2.
// All patterns below re-verified conflict-free(<=2-way) under this swizzle.
__device__ __forceinline__ int swz(int s) {
  int m = s ^ ((s >> 6) & 63);
  return m ^ ((m >> 3) & 7);
}

__device__ __forceinline__ v2 block_reduce_sum2(v2 v, v2* red) {
  const int tid = threadIdx.x;
#pragma unroll
  for (int off = 32; off > 0; off >>= 1) {
    v.x += __shfl_down(v.x, off, 64);
    v.y += __shfl_down(v.y, off, 64);
  }
  if ((tid & 63) == 0) red[tid >> 6] = v;
  __syncthreads();
  if (tid == 0) {
    v2 s = sp(0.f);
#pragma unroll
    for (int i = 0; i < NT / 64; ++i) s += red[i];
    red[0] = s;
  }
  __syncthreads();
  v2 r = red[0];
  __syncthreads();
  return r;
}

// Packed complex pair update for two rows at once (v_pk_fma_f32 material).
__device__ __forceinline__ void apply_pair(v2& r0, v2& i0, v2& r1, v2& i1,
    const float2 u00, const float2 u01, const float2 u10, const float2 u11) {
  v2 nr0 = pkfma(i1, -u01.y, pkfma(r1, u01.x, pkfma(i0, -u00.y, r0 * sp(u00.x))));
  v2 ni0 = pkfma(r1,  u01.y, pkfma(i1, u01.x, pkfma(r0,  u00.y, i0 * sp(u00.x))));
  v2 nr1 = pkfma(i1, -u11.y, pkfma(r1, u11.x, pkfma(i0, -u10.y, r0 * sp(u10.x))));
  v2 ni1 = pkfma(r1,  u11.y, pkfma(i1, u11.x, pkfma(r0,  u10.y, i0 * sp(u10.x))));
  r0 = nr0; i0 = ni0; r1 = nr1; i1 = ni1;
}

// Pass RT: reg slot-bit i holds z-bit (9-3*RT)+i -> qubit (2+3*RT)-i.
template <int RT>
__device__ __forceinline__ void gates3(v2 re[8], v2 im[8], const float2* GL) {
#pragma unroll
  for (int i = 0; i < 3; ++i) {
    const int q = 2 + 3 * RT - i;
    const float2 u00 = GL[q * 4 + 0], u01 = GL[q * 4 + 1];
    const float2 u10 = GL[q * 4 + 2], u11 = GL[q * 4 + 3];
#pragma unroll
    for (int pe = 0; pe < 4; ++pe) {
      const int e0 = ((pe >> i) << (i + 1)) | (pe & ((1 << i) - 1));
      const int e1 = e0 | (1 << i);
      apply_pair(re[e0], im[e0], re[e1], im[e1], u00, u01, u10, u11);
    }
  }
}

#define LOAD8(ADDR)                         \
  _Pragma("unroll")                         \
  for (int j = 0; j < 8; ++j) {             \
    const float4 v = st[ADDR[j]];           \
    re[j] = mkv2(v.x, v.y);                 \
    im[j] = mkv2(v.z, v.w);                 \
  }
#define STORE8(ADDR)                        \
  _Pragma("unroll")                         \
  for (int j = 0; j < 8; ++j)               \
    st[ADDR[j]] = make_float4(re[j].x, re[j].y, im[j].x, im[j].y);

__global__ __launch_bounds__(NT, 4) void qsim_kernel(
    const float* __restrict__ x, const float* __restrict__ w,
    float* __restrict__ out) {
  extern __shared__ __align__(16) char smem[];
  float4* st   = (float4*)smem;                  // 64 KB: unit=(re0,re1,im0,im1)
  float2* gmat = (float2*)(st + DIM);            // 1.5 KB
  v2*     red  = (v2*)(gmat + NLAYER * NQ * 4);  // 64 B

  const int t = threadIdx.x;
  const int lane = t & 63, wave = t >> 6;
  const int a = t & 7, b = (t >> 3) & 7;
  const long r0 = 2L * blockIdx.x;

  // --- gate matrices (48 gates, one thread each) ---
  if (t < NLAYER * NQ) {
    const float* wp = w + t * 3;
    float phi = wp[0], th = wp[1], om = wp[2];
    float sn, cc, sa, ca, sb, cb;
    sincosf(0.5f * th, &sn, &cc);
    sincosf(0.5f * (phi + om), &sa, &ca);
    sincosf(0.5f * (phi - om), &sb, &cb);
    float2* g = &gmat[t * 4];
    g[0] = make_float2(ca * cc, -sa * cc);   // U00
    g[1] = make_float2(-cb * sn, -sb * sn);  // U01
    g[2] = make_float2(cb * sn, -sb * sn);   // U10
    g[3] = make_float2(ca * cc, sa * cc);    // U11
  }

  // --- load 8 consecutive x from each of 2 rows, norms, encode ---
  const float4* xa = (const float4*)(x + r0 * DIM) + t * 2;
  const float4* xb = (const float4*)(x + (r0 + 1) * DIM) + t * 2;
  const float4 a0 = xa[0], a1 = xa[1], b0 = xb[0], b1 = xb[1];
  const float va[8] = {a0.x, a0.y, a0.z, a0.w, a1.x, a1.y, a1.z, a1.w};
  const float vb[8] = {b0.x, b0.y, b0.z, b0.w, b1.x, b1.y, b1.z, b1.w};
  v2 ss = sp(0.f);
#pragma unroll
  for (int e = 0; e < 8; ++e) { ss.x += va[e] * va[e]; ss.y += vb[e] * vb[e]; }
  const v2 nsq = block_reduce_sum2(ss, red);   // barriers also cover gmat init
  const float n0 = sqrtf(nsq.x), n1 = sqrtf(nsq.y);
  const bool ok0 = n0 > 1e-10f, ok1 = n1 > 1e-10f;
  const float i0f = ok0 ? 1.0f / n0 : 0.f, i1f = ok1 ? 1.0f / n1 : 0.f;
  // init layout = identity under swz (z at position swz(z))
#pragma unroll
  for (int e = 0; e < 8; ++e)
    st[swz(t * 8 + e)] = make_float4(ok0 ? va[e] * i0f : 0.015625f,
                                     ok1 ? vb[e] * i1f : 0.015625f, 0.f, 0.f);

  // read/write partitions (fixed layout, rotating patterns), all swizzled:
  // p0: j = z{9-11}; p1: j = z{6-8}; p2: j = z{3-5}; p3: j = z{0-2};
  // gd: CNOT-perm gather composed with p0.
  int p0[8], p1[8], p2[8], p3[8], gd[8];
#pragma unroll
  for (int j = 0; j < 8; ++j) {
    p0[j] = swz(t | (j << 9));
    p1[j] = swz(lane | (j << 6) | (wave << 9));
    p2[j] = swz(a | (j << 3) | (b << 6) | (wave << 9));
    p3[j] = swz(j | (a << 3) | (b << 6) | (wave << 9));
    gd[j] = swz(sfun(t | (j << 9)));
  }
  __syncthreads();

  v2 re[8], im[8];
#pragma unroll
  for (int L = 0; L < NLAYER; ++L) {
    const float2* GL = &gmat[L * NQ * 4];

    // RT0: bits 9-11 (qubits 2,1,0). L>=1: read fuses prev layer's CNOT perm.
    if (L == 0) {
      LOAD8(p0)
    } else {
      LOAD8(gd)
    }
    gates3<0>(re, im, GL);
    if (L > 0) __syncthreads();  // all gathers done before in-place writes
    STORE8(p0)
    __syncthreads();

    // RT1: bits 6-8 (qubits 5,4,3) — in-place
    LOAD8(p1)
    gates3<1>(re, im, GL);
    STORE8(p1)
    __syncthreads();

    // RT2: bits 3-5 (qubits 8,7,6) — in-place
    LOAD8(p2)
    gates3<2>(re, im, GL);
    STORE8(p2)
    __syncthreads();

    // RT3: bits 0-2 (qubits 11,10,9) — in-place
    LOAD8(p3)
    gates3<3>(re, im, GL);
    STORE8(p3)
    __syncthreads();
  }

  // --- output: final perm fused into gather; probs + renormalize, 2 rows ---
  float q0[8], q1[8];
  v2 ps = sp(0.f);
#pragma unroll
  for (int k = 0; k < 8; ++k) {
    const float4 v = st[gd[k]];
    q0[k] = v.x * v.x + v.z * v.z;
    q1[k] = v.y * v.y + v.w * v.w;
    ps.x += q0[k]; ps.y += q1[k];
  }
  const v2 tot = block_reduce_sum2(ps, red);
  const bool k0 = tot.x > 1e-10f, k1 = tot.y > 1e-10f;
  const float t0 = k0 ? 1.0f / tot.x : 0.f, t1 = k1 ? 1.0f / tot.y : 0.f;
  float* o0 = out + r0 * DIM;
  float* o1 = out + (r0 + 1) * DIM;
#pragma unroll
  for (int k = 0; k < 8; ++k) {
    o0[t + k * NT] = k0 ? q0[k] * t0 : (1.0f / DIM);
    o1[t + k * NT] = k1 ? q1[k] * t1 : (1.0f / DIM);
  }
}

extern "C" void kernel_launch(void* const* d_in, const int* in_sizes, int n_in,
                              void* d_out, int out_size, void* d_ws, size_t ws_size,
                              hipStream_t stream) {
  const float* x = (const float*)d_in[0];
  const float* w = (const float*)d_in[1];
  float* out = (float*)d_out;
  const int B = in_sizes[0] / DIM;
  const size_t smem = DIM * sizeof(float4) + NLAYER * NQ * 4 * sizeof(float2)
                    + (NT / 64) * sizeof(v2);
  qsim_kernel<<<B / 2, NT, smem, stream>>>(x, w, out);
}